// Round 9
// baseline (159.553 us; speedup 1.0000x reference)
//
#include <hip/hip_runtime.h>

// 3-layer GCN on MI355X.
// Structure (R5): per-node normalization factored (store v*dinv), so
// aggregation is an unweighted add-gather and adjacency needs no count/scan:
//   memset(cursor) -> k_fill (bucketed adjacency, cursor ends = in-degree)
//   -> k_prep (dinv, xs = x*dinv) -> k_gemm12 (agg1 + L1 + L2 linear -> t2s)
//   -> k_agg2 (gather t2s, relu, dot W3 -> t3s) -> k_agg3 (gather t3s -> out).
// R9: gemm12 register tile 4 nodes x 4 cols (MB=32) — phase B LDS bytes/MAC
// 3B -> 2B and ds_read count halved per MAC; flips phase B to VALU-bound.
// Lessons: R3 atomic scatter=186us; R4 grid.sync~100us each; R7 register W2 =
// L2-BW-bound (8x per-wave redundancy); macro params must not be named 'w'.

constexpr int NN  = 20000;  // nodes
constexpr int NE  = 320000; // edges
constexpr int F0  = 10;     // input feats
constexpr int F1  = 256;    // layer1 out
constexpr int F2  = 128;    // layer2 out
constexpr int MB  = 32;     // nodes per gemm12 tile (R9: was 16)
constexpr int CAP = 64;     // bucket capacity (max in-deg ~36, P(>=64)~2e-18)

// ---------- adjacency fill ----------

__global__ void k_fill(const int* __restrict__ src, const int* __restrict__ dst,
                       int* cursor, int* __restrict__ col) {
  int e = blockIdx.x * 256 + threadIdx.x;
  if (e >= NE) return;
  const int d = dst[e], s = src[e];
  const int pos = atomicAdd(&cursor[d], 1) & (CAP - 1);
  col[d * CAP + pos] = s;
}

// ---------- dinv = rsqrt(deg+1); xs = x * dinv ----------

__global__ void k_prep(const float* __restrict__ x, const int* __restrict__ cursor,
                       float* __restrict__ dinv, float* __restrict__ xs) {
  int i = blockIdx.x * 256 + threadIdx.x;
  if (i >= NN * F0) return;
  const int n = (int)((unsigned)i / F0);
  const float di = rsqrtf((float)(cursor[n] + 1));
  xs[i] = x[i] * di;
  if (i - n * F0 == 0) dinv[n] = di;
}

// ---------- fused: a1 (LDS) -> h1 = relu(a1 W1 + b1) (LDS) -> t2s = dinv*(h1 W2)

__global__ __launch_bounds__(256) void k_gemm12(
    const float* __restrict__ xs, const float* __restrict__ dinv,
    const int* __restrict__ cursor, const int* __restrict__ col,
    const float* __restrict__ W1, const float* __restrict__ b1,
    const float* __restrict__ W2, float* __restrict__ t2s) {
  __shared__ float alds[MB * F0];     // 1.25 KB
  __shared__ float h1[MB][F1 + 4];    // 33.3 KB, k-contiguous per node
  __shared__ float w2lds[32 * F2];    // 16 KB, one 32-row chunk of W2
  const int tid = threadIdx.x;
  const int n0 = blockIdx.x * MB;
  // stage 0: layer-1 aggregation into LDS; 320 items over 256 threads
  for (int i = tid; i < MB * F0; i += 256) {
    const int m = (int)((unsigned)i / F0);
    const int f = i - m * F0;
    const int n = n0 + m;
    const int deg = cursor[n];
    const int base = n * CAP;
    float acc = xs[n * F0 + f];  // self-loop
    int k = 0;
    for (; k + 3 < deg; k += 4)
      acc += xs[col[base + k] * F0 + f] + xs[col[base + k + 1] * F0 + f] +
             xs[col[base + k + 2] * F0 + f] + xs[col[base + k + 3] * F0 + f];
    for (; k < deg; ++k) acc += xs[col[base + k] * F0 + f];
    alds[i] = dinv[n] * acc;
  }
  __syncthreads();
  {  // phase A: thread = layer-1 channel c; h1[m][c] stride-1 in c
    const int c = tid;
    float w1r[F0];
#pragma unroll
    for (int k = 0; k < F0; ++k) w1r[k] = W1[k * F1 + c];
    const float bb = b1[c];
#pragma unroll
    for (int m = 0; m < MB; ++m) {
      float acc = bb;
#pragma unroll
      for (int k = 0; k < F0; ++k) acc += alds[m * F0 + k] * w1r[k];
      h1[m][c] = fmaxf(acc, 0.f);
    }
  }
  // phase B: 4 nodes x 4 cols per thread; W2 LDS-staged in 32-row chunks,
  // h1 and w2 read as float4 (4 k per read). 64 MAC per 128 B LDS.
  const int cg_ = tid & 31;       // 32 col-groups * 4 cols = 128
  const int m0 = (tid >> 5) * 4;  // 8 node-groups * 4 nodes = 32
  float a[4][4] = {{0.f, 0.f, 0.f, 0.f}, {0.f, 0.f, 0.f, 0.f},
                   {0.f, 0.f, 0.f, 0.f}, {0.f, 0.f, 0.f, 0.f}};
#define FMA1(i, hv, vw)                                             \
  a[i][0] += (hv) * (vw).x; a[i][1] += (hv) * (vw).y;               \
  a[i][2] += (hv) * (vw).z; a[i][3] += (hv) * (vw).w;
  for (int kc = 0; kc < F1 / 32; ++kc) {
    __syncthreads();  // prev chunk consumed (kc=0: h1 written by phase A)
    {  // stage 32x128 chunk: 1024 float4, 4 per thread, coalesced
      const float4* gsrc = (const float4*)(W2 + kc * 32 * F2);
      float4* ldst = (float4*)w2lds;
#pragma unroll
      for (int i = 0; i < 4; ++i) ldst[tid + 256 * i] = gsrc[tid + 256 * i];
    }
    __syncthreads();
#pragma unroll
    for (int kk = 0; kk < 32; kk += 4) {
      const int k = kc * 32 + kk;
      const float4 w0 = *(const float4*)&w2lds[(kk + 0) * F2 + cg_ * 4];
      const float4 w1v = *(const float4*)&w2lds[(kk + 1) * F2 + cg_ * 4];
      const float4 w2v = *(const float4*)&w2lds[(kk + 2) * F2 + cg_ * 4];
      const float4 w3v = *(const float4*)&w2lds[(kk + 3) * F2 + cg_ * 4];
      const float4 h0 = *(const float4*)&h1[m0 + 0][k];
      const float4 hv1 = *(const float4*)&h1[m0 + 1][k];
      const float4 hv2 = *(const float4*)&h1[m0 + 2][k];
      const float4 hv3 = *(const float4*)&h1[m0 + 3][k];
      FMA1(0, h0.x, w0);  FMA1(0, h0.y, w1v);  FMA1(0, h0.z, w2v);  FMA1(0, h0.w, w3v);
      FMA1(1, hv1.x, w0); FMA1(1, hv1.y, w1v); FMA1(1, hv1.z, w2v); FMA1(1, hv1.w, w3v);
      FMA1(2, hv2.x, w0); FMA1(2, hv2.y, w1v); FMA1(2, hv2.z, w2v); FMA1(2, hv2.w, w3v);
      FMA1(3, hv3.x, w0); FMA1(3, hv3.y, w1v); FMA1(3, hv3.z, w2v); FMA1(3, hv3.w, w3v);
    }
  }
#undef FMA1
#pragma unroll
  for (int i = 0; i < 4; ++i) {
    const float dd = dinv[n0 + m0 + i];
    *(float4*)&t2s[(size_t)(n0 + m0 + i) * F2 + cg_ * 4] =
        make_float4(a[i][0] * dd, a[i][1] * dd, a[i][2] * dd, a[i][3] * dd);
  }
}

// ---------- layer-2 aggregation + layer-3 transform (one wave per node) ----

__global__ __launch_bounds__(256) void k_agg2(
    const float* __restrict__ t2s, const float* __restrict__ dinv,
    const int* __restrict__ cursor, const int* __restrict__ col,
    const float* __restrict__ b2, const float* __restrict__ W3,
    float* __restrict__ t3s) {
  const int n = __builtin_amdgcn_readfirstlane((blockIdx.x * 256 + threadIdx.x) >> 6);
  const int lane = threadIdx.x & 63;
  if (n >= NN) return;
  const int deg = cursor[n];
  const int base = n * CAP;
  const int fx = lane * 2;
  const float2 vs = *(const float2*)&t2s[(size_t)n * F2 + fx];
  float ax = vs.x, ay = vs.y;
  int k = 0;
  for (; k + 7 < deg; k += 8) {  // 8 coalesced 512B gathers in flight
    const int s0 = col[base + k],     s1 = col[base + k + 1];
    const int s2 = col[base + k + 2], s3 = col[base + k + 3];
    const int s4 = col[base + k + 4], s5 = col[base + k + 5];
    const int s6 = col[base + k + 6], s7 = col[base + k + 7];
    const float2 v0 = *(const float2*)&t2s[(size_t)s0 * F2 + fx];
    const float2 v1 = *(const float2*)&t2s[(size_t)s1 * F2 + fx];
    const float2 v2 = *(const float2*)&t2s[(size_t)s2 * F2 + fx];
    const float2 v3 = *(const float2*)&t2s[(size_t)s3 * F2 + fx];
    const float2 v4 = *(const float2*)&t2s[(size_t)s4 * F2 + fx];
    const float2 v5 = *(const float2*)&t2s[(size_t)s5 * F2 + fx];
    const float2 v6 = *(const float2*)&t2s[(size_t)s6 * F2 + fx];
    const float2 v7 = *(const float2*)&t2s[(size_t)s7 * F2 + fx];
    ax += ((v0.x + v1.x) + (v2.x + v3.x)) + ((v4.x + v5.x) + (v6.x + v7.x));
    ay += ((v0.y + v1.y) + (v2.y + v3.y)) + ((v4.y + v5.y) + (v6.y + v7.y));
  }
  for (; k < deg; ++k) {
    const float2 v = *(const float2*)&t2s[(size_t)col[base + k] * F2 + fx];
    ax += v.x;
    ay += v.y;
  }
  const float di = dinv[n];
  const float hx = fmaxf(di * ax + b2[fx], 0.f);
  const float hy = fmaxf(di * ay + b2[fx + 1], 0.f);
  float p = hx * W3[fx] + hy * W3[fx + 1];
#pragma unroll
  for (int off = 32; off > 0; off >>= 1) p += __shfl_down(p, off);
  if (lane == 0) t3s[n] = di * p;
}

// ---------- layer-3 aggregation ----------

__global__ void k_agg3(const float* __restrict__ t3s, const float* __restrict__ dinv,
                       const int* __restrict__ cursor, const int* __restrict__ col,
                       const float* __restrict__ b3, float* __restrict__ out) {
  int n = blockIdx.x * 256 + threadIdx.x;
  if (n >= NN) return;
  const int deg = cursor[n];
  const int base = n * CAP;
  float acc = t3s[n];
  int k = 0;
  for (; k + 7 < deg; k += 8)
    acc += ((t3s[col[base + k]] + t3s[col[base + k + 1]]) +
            (t3s[col[base + k + 2]] + t3s[col[base + k + 3]])) +
           ((t3s[col[base + k + 4]] + t3s[col[base + k + 5]]) +
            (t3s[col[base + k + 6]] + t3s[col[base + k + 7]]));
  for (; k < deg; ++k) acc += t3s[col[base + k]];
  out[n] = dinv[n] * acc + b3[0];
}

extern "C" void kernel_launch(void* const* d_in, const int* in_sizes, int n_in,
                              void* d_out, int out_size, void* d_ws, size_t ws_size,
                              hipStream_t stream) {
  const float* x = (const float*)d_in[0];
  const int* ei = (const int*)d_in[1];
  const int* srcv = ei;       // edge_index[0]
  const int* dstv = ei + NE;  // edge_index[1]
  const float* W1 = (const float*)d_in[2];
  const float* b1 = (const float*)d_in[3];
  const float* W2 = (const float*)d_in[4];
  const float* b2 = (const float*)d_in[5];
  const float* W3 = (const float*)d_in[6];
  const float* b3 = (const float*)d_in[7];
  float* out = (float*)d_out;

  char* w = (char*)d_ws;
  auto alloc = [&](size_t bytes) -> void* {
    void* p = (void*)w;
    w += (bytes + 255) & ~(size_t)255;
    return p;
  };
  int*   cursor = (int*)  alloc(NN * 4);
  float* dinv   = (float*)alloc(NN * 4);
  float* xs     = (float*)alloc((size_t)NN * F0 * 4);
  int*   col    = (int*)  alloc((size_t)NN * CAP * 4);
  float* t2s    = (float*)alloc((size_t)NN * F2 * 4);
  float* t3s    = (float*)alloc(NN * 4);

  (void)hipMemsetAsync(cursor, 0, NN * 4, stream);
  k_fill<<<(NE + 255) / 256, 256, 0, stream>>>(srcv, dstv, cursor, col);
  k_prep<<<(NN * F0 + 255) / 256, 256, 0, stream>>>(x, cursor, dinv, xs);
  k_gemm12<<<NN / MB, 256, 0, stream>>>(xs, dinv, cursor, col, W1, b1, W2, t2s);
  k_agg2<<<(NN + 3) / 4, 256, 0, stream>>>(t2s, dinv, cursor, col, b2, W3, t3s);
  k_agg3<<<(NN + 255) / 256, 256, 0, stream>>>(t3s, dinv, cursor, col, b3, out);
}

// Round 11
// 158.880 us; speedup vs baseline: 1.0042x; 1.0042x over previous
//
#include <hip/hip_runtime.h>

// 3-layer GCN on MI355X.
// Structure (R5): per-node normalization factored (store v*dinv), so
// aggregation is an unweighted add-gather and adjacency needs no count/scan:
//   memset(cursor) -> k_fill (bucketed adjacency, cursor ends = in-degree)
//   -> k_prep (dinv, xs = x*dinv) -> k_gemm12 (agg1 + L1 + L2 linear -> t2s)
//   -> k_agg2 (gather t2s, relu, dot W3 -> t3s) -> k_agg3 (gather t3s -> out).
// R11: R10's wave-partitioned-W2 phase B with CORRECT wave math (4 waves per
// 256-thread block, not 8): wave owns 32 cols, lane = 4 nodes x 4 cols.
// W2 read once per block from L2, zero barriers in the k-loop.
// Lessons: R3 atomic scatter=186us; R4 grid.sync~100us each; R7 register W2
// with 8x intra-block redundancy = L2-BW-bound; R9 chunk barriers at <4
// blocks/CU = stall; R10 wrote only half the cols (wave count!).

constexpr int NN  = 20000;  // nodes
constexpr int NE  = 320000; // edges
constexpr int F0  = 10;     // input feats
constexpr int F1  = 256;    // layer1 out
constexpr int F2  = 128;    // layer2 out
constexpr int MB  = 32;     // nodes per gemm12 tile
constexpr int CAP = 64;     // bucket capacity (max in-deg ~36, P(>=64)~2e-18)

// ---------- adjacency fill ----------

__global__ void k_fill(const int* __restrict__ src, const int* __restrict__ dst,
                       int* cursor, int* __restrict__ col) {
  int e = blockIdx.x * 256 + threadIdx.x;
  if (e >= NE) return;
  const int d = dst[e], s = src[e];
  const int pos = atomicAdd(&cursor[d], 1) & (CAP - 1);
  col[d * CAP + pos] = s;
}

// ---------- dinv = rsqrt(deg+1); xs = x * dinv ----------

__global__ void k_prep(const float* __restrict__ x, const int* __restrict__ cursor,
                       float* __restrict__ dinv, float* __restrict__ xs) {
  int i = blockIdx.x * 256 + threadIdx.x;
  if (i >= NN * F0) return;
  const int n = (int)((unsigned)i / F0);
  const float di = rsqrtf((float)(cursor[n] + 1));
  xs[i] = x[i] * di;
  if (i - n * F0 == 0) dinv[n] = di;
}

// ---------- fused: a1 (LDS) -> h1 = relu(a1 W1 + b1) (LDS) -> t2s = dinv*(h1 W2)

__global__ __launch_bounds__(256) void k_gemm12(
    const float* __restrict__ xs, const float* __restrict__ dinv,
    const int* __restrict__ cursor, const int* __restrict__ col,
    const float* __restrict__ W1, const float* __restrict__ b1,
    const float* __restrict__ W2, float* __restrict__ t2s) {
  __shared__ float alds[MB * F0];     // 1.25 KB
  __shared__ float h1[MB][F1 + 4];    // 33.3 KB; stride 260 -> phase-B reads
                                      // are 8 distinct b128 spans tiling all
                                      // 32 banks + 8-lane broadcast: conflict-free
  const int tid = threadIdx.x;
  const int n0 = blockIdx.x * MB;
  // stage 0: layer-1 aggregation into LDS; 320 items over 256 threads
  for (int i = tid; i < MB * F0; i += 256) {
    const int m = (int)((unsigned)i / F0);
    const int f = i - m * F0;
    const int n = n0 + m;
    const int deg = cursor[n];
    const int base = n * CAP;
    float acc = xs[n * F0 + f];  // self-loop
    int k = 0;
    for (; k + 3 < deg; k += 4)
      acc += xs[col[base + k] * F0 + f] + xs[col[base + k + 1] * F0 + f] +
             xs[col[base + k + 2] * F0 + f] + xs[col[base + k + 3] * F0 + f];
    for (; k < deg; ++k) acc += xs[col[base + k] * F0 + f];
    alds[i] = dinv[n] * acc;
  }
  __syncthreads();
  {  // phase A: thread = layer-1 channel c; h1[m][c] stride-1 in c
    const int c = tid;
    float w1r[F0];
#pragma unroll
    for (int k = 0; k < F0; ++k) w1r[k] = W1[k * F1 + c];
    const float bb = b1[c];
#pragma unroll
    for (int m = 0; m < MB; ++m) {
      float acc = bb;
#pragma unroll
      for (int k = 0; k < F0; ++k) acc += alds[m * F0 + k] * w1r[k];
      h1[m][c] = fmaxf(acc, 0.f);
    }
  }
  __syncthreads();  // the LAST barrier — phase B streams with no syncs
  // phase B: wave wv (of 4) owns cols [32*wv, 32*wv+32) -> W2 read ONCE per
  // block. Lane: nodes {g, g+8, g+16, g+24} x 4 cols; 16 acc; 64 FMA per 4k.
  const int wv = tid >> 6;   // 4 waves
  const int l  = tid & 63;
  const int q  = l & 7;      // col-quad within the wave's 32-col slice
  const int g  = l >> 3;     // node-group base: nodes g + 8*i, i=0..3
  const int c0 = wv * 32 + q * 4;
  float a[4][4] = {{0.f, 0.f, 0.f, 0.f}, {0.f, 0.f, 0.f, 0.f},
                   {0.f, 0.f, 0.f, 0.f}, {0.f, 0.f, 0.f, 0.f}};
  const float* w2p = W2 + c0;
#define FMA4(i, hv, wv4)                                            \
  a[i][0] += (hv) * (wv4).x; a[i][1] += (hv) * (wv4).y;             \
  a[i][2] += (hv) * (wv4).z; a[i][3] += (hv) * (wv4).w;
#pragma unroll 4
  for (int k = 0; k < F1; k += 4) {
    const float4 w_0 = *(const float4*)(w2p + (size_t)(k + 0) * F2);
    const float4 w_1 = *(const float4*)(w2p + (size_t)(k + 1) * F2);
    const float4 w_2 = *(const float4*)(w2p + (size_t)(k + 2) * F2);
    const float4 w_3 = *(const float4*)(w2p + (size_t)(k + 3) * F2);
    const float4 h0 = *(const float4*)&h1[g][k];
    const float4 hA = *(const float4*)&h1[g + 8][k];
    const float4 hB = *(const float4*)&h1[g + 16][k];
    const float4 hC = *(const float4*)&h1[g + 24][k];
    FMA4(0, h0.x, w_0); FMA4(0, h0.y, w_1); FMA4(0, h0.z, w_2); FMA4(0, h0.w, w_3);
    FMA4(1, hA.x, w_0); FMA4(1, hA.y, w_1); FMA4(1, hA.z, w_2); FMA4(1, hA.w, w_3);
    FMA4(2, hB.x, w_0); FMA4(2, hB.y, w_1); FMA4(2, hB.z, w_2); FMA4(2, hB.w, w_3);
    FMA4(3, hC.x, w_0); FMA4(3, hC.y, w_1); FMA4(3, hC.z, w_2); FMA4(3, hC.w, w_3);
  }
#undef FMA4
#pragma unroll
  for (int i = 0; i < 4; ++i) {
    const int n = n0 + g + 8 * i;
    const float dd = dinv[n];
    *(float4*)&t2s[(size_t)n * F2 + c0] =
        make_float4(a[i][0] * dd, a[i][1] * dd, a[i][2] * dd, a[i][3] * dd);
  }
}

// ---------- layer-2 aggregation + layer-3 transform (one wave per node) ----

__global__ __launch_bounds__(256) void k_agg2(
    const float* __restrict__ t2s, const float* __restrict__ dinv,
    const int* __restrict__ cursor, const int* __restrict__ col,
    const float* __restrict__ b2, const float* __restrict__ W3,
    float* __restrict__ t3s) {
  const int n = __builtin_amdgcn_readfirstlane((blockIdx.x * 256 + threadIdx.x) >> 6);
  const int lane = threadIdx.x & 63;
  if (n >= NN) return;
  const int deg = cursor[n];
  const int base = n * CAP;
  const int fx = lane * 2;
  const float2 vs = *(const float2*)&t2s[(size_t)n * F2 + fx];
  float ax = vs.x, ay = vs.y;
  int k = 0;
  for (; k + 7 < deg; k += 8) {  // 8 coalesced 512B gathers in flight
    const int s0 = col[base + k],     s1 = col[base + k + 1];
    const int s2 = col[base + k + 2], s3 = col[base + k + 3];
    const int s4 = col[base + k + 4], s5 = col[base + k + 5];
    const int s6 = col[base + k + 6], s7 = col[base + k + 7];
    const float2 v0 = *(const float2*)&t2s[(size_t)s0 * F2 + fx];
    const float2 v1 = *(const float2*)&t2s[(size_t)s1 * F2 + fx];
    const float2 v2 = *(const float2*)&t2s[(size_t)s2 * F2 + fx];
    const float2 v3 = *(const float2*)&t2s[(size_t)s3 * F2 + fx];
    const float2 v4 = *(const float2*)&t2s[(size_t)s4 * F2 + fx];
    const float2 v5 = *(const float2*)&t2s[(size_t)s5 * F2 + fx];
    const float2 v6 = *(const float2*)&t2s[(size_t)s6 * F2 + fx];
    const float2 v7 = *(const float2*)&t2s[(size_t)s7 * F2 + fx];
    ax += ((v0.x + v1.x) + (v2.x + v3.x)) + ((v4.x + v5.x) + (v6.x + v7.x));
    ay += ((v0.y + v1.y) + (v2.y + v3.y)) + ((v4.y + v5.y) + (v6.y + v7.y));
  }
  for (; k < deg; ++k) {
    const float2 v = *(const float2*)&t2s[(size_t)col[base + k] * F2 + fx];
    ax += v.x;
    ay += v.y;
  }
  const float di = dinv[n];
  const float hx = fmaxf(di * ax + b2[fx], 0.f);
  const float hy = fmaxf(di * ay + b2[fx + 1], 0.f);
  float p = hx * W3[fx] + hy * W3[fx + 1];
#pragma unroll
  for (int off = 32; off > 0; off >>= 1) p += __shfl_down(p, off);
  if (lane == 0) t3s[n] = di * p;
}

// ---------- layer-3 aggregation ----------

__global__ void k_agg3(const float* __restrict__ t3s, const float* __restrict__ dinv,
                       const int* __restrict__ cursor, const int* __restrict__ col,
                       const float* __restrict__ b3, float* __restrict__ out) {
  int n = blockIdx.x * 256 + threadIdx.x;
  if (n >= NN) return;
  const int deg = cursor[n];
  const int base = n * CAP;
  float acc = t3s[n];
  int k = 0;
  for (; k + 7 < deg; k += 8)
    acc += ((t3s[col[base + k]] + t3s[col[base + k + 1]]) +
            (t3s[col[base + k + 2]] + t3s[col[base + k + 3]])) +
           ((t3s[col[base + k + 4]] + t3s[col[base + k + 5]]) +
            (t3s[col[base + k + 6]] + t3s[col[base + k + 7]]));
  for (; k < deg; ++k) acc += t3s[col[base + k]];
  out[n] = dinv[n] * acc + b3[0];
}

extern "C" void kernel_launch(void* const* d_in, const int* in_sizes, int n_in,
                              void* d_out, int out_size, void* d_ws, size_t ws_size,
                              hipStream_t stream) {
  const float* x = (const float*)d_in[0];
  const int* ei = (const int*)d_in[1];
  const int* srcv = ei;       // edge_index[0]
  const int* dstv = ei + NE;  // edge_index[1]
  const float* W1 = (const float*)d_in[2];
  const float* b1 = (const float*)d_in[3];
  const float* W2 = (const float*)d_in[4];
  const float* b2 = (const float*)d_in[5];
  const float* W3 = (const float*)d_in[6];
  const float* b3 = (const float*)d_in[7];
  float* out = (float*)d_out;

  char* w = (char*)d_ws;
  auto alloc = [&](size_t bytes) -> void* {
    void* p = (void*)w;
    w += (bytes + 255) & ~(size_t)255;
    return p;
  };
  int*   cursor = (int*)  alloc(NN * 4);
  float* dinv   = (float*)alloc(NN * 4);
  float* xs     = (float*)alloc((size_t)NN * F0 * 4);
  int*   col    = (int*)  alloc((size_t)NN * CAP * 4);
  float* t2s    = (float*)alloc((size_t)NN * F2 * 4);
  float* t3s    = (float*)alloc(NN * 4);

  (void)hipMemsetAsync(cursor, 0, NN * 4, stream);
  k_fill<<<(NE + 255) / 256, 256, 0, stream>>>(srcv, dstv, cursor, col);
  k_prep<<<(NN * F0 + 255) / 256, 256, 0, stream>>>(x, cursor, dinv, xs);
  k_gemm12<<<NN / MB, 256, 0, stream>>>(xs, dinv, cursor, col, W1, b1, W2, t2s);
  k_agg2<<<(NN + 3) / 4, 256, 0, stream>>>(t2s, dinv, cursor, col, b2, W3, t3s);
  k_agg3<<<(NN + 255) / 256, 256, 0, stream>>>(t3s, dinv, cursor, col, b3, out);
}

// Round 12
// 152.410 us; speedup vs baseline: 1.0469x; 1.0425x over previous
//
#include <hip/hip_runtime.h>

// 3-layer GCN on MI355X.
// Structure: per-node normalization factored (aggregate pre-scaled values),
// adjacency = fixed-capacity buckets, no count/scan:
//   memset(cursor) -> k_fill (cursor ends = in-degree)
//   -> k_gemm12 (agg1 from x with on-the-fly dinv + L1 + L2 linear -> t2s)
//   -> k_agg2 (gather t2s, relu, dot W3 -> t3s) -> k_agg3 (gather -> out).
// R12: gemm12 back to R8-exact (MB=16 won: 1250 blocks beats 625 — R9/R11's
// MB=32 both +6us from grid tail); k_prep deleted (dinv computed from cursor
// everywhere); agg2 = 2 nodes/wave, float4 lanes.
// Lessons: R3 atomic scatter=186us; R4 grid.sync~100us; R7 register W2 =
// L2-BW-bound; R9/R11 MB=32 grid-tail; R10 wave-count bug; macro params != 'w'.

constexpr int NN  = 20000;  // nodes
constexpr int NE  = 320000; // edges
constexpr int F0  = 10;     // input feats
constexpr int F1  = 256;    // layer1 out
constexpr int F2  = 128;    // layer2 out
constexpr int MB  = 16;     // nodes per gemm12 tile
constexpr int CAP = 64;     // bucket capacity (max in-deg ~36, P(>=64)~2e-18)

// ---------- adjacency fill ----------

__global__ void k_fill(const int* __restrict__ src, const int* __restrict__ dst,
                       int* cursor, int* __restrict__ col) {
  int e = blockIdx.x * 256 + threadIdx.x;
  if (e >= NE) return;
  const int d = dst[e], s = src[e];
  const int pos = atomicAdd(&cursor[d], 1) & (CAP - 1);
  col[d * CAP + pos] = s;
}

// ---------- fused: a1 (LDS) -> h1 = relu(a1 W1 + b1) (LDS) -> t2s = dinv*(h1 W2)

__global__ __launch_bounds__(256) void k_gemm12(
    const float* __restrict__ x, const int* __restrict__ cursor,
    const int* __restrict__ col, const float* __restrict__ W1,
    const float* __restrict__ b1, const float* __restrict__ W2,
    float* __restrict__ t2s) {
  __shared__ float alds[MB * F0];     // 640 B
  __shared__ float h1[MB][F1 + 4];    // 16.6 KB, k-contiguous per node
  __shared__ float w2lds[32 * F2];    // 16 KB, one 32-row chunk of W2
  const int tid = threadIdx.x;
  const int n0 = blockIdx.x * MB;
  // stage 0: layer-1 aggregation into LDS; dinv computed on the fly from
  // cursor (k_prep deleted). f-lanes of one node load the same cursor[s]
  // (broadcast) — one fetch per neighbor.
  {
    const int m = tid >> 4;
    const int f = tid & 15;
    if (f < F0) {
      const int n = n0 + m;
      const int deg = cursor[n];
      const int base = n * CAP;
      const float di = rsqrtf((float)(deg + 1));
      float acc = x[n * F0 + f] * di;  // self-loop (pre-scaled by own dinv)
      int k = 0;
      for (; k + 3 < deg; k += 4) {
        const int s0 = col[base + k],     s1 = col[base + k + 1];
        const int s2 = col[base + k + 2], s3 = col[base + k + 3];
        const float d0 = rsqrtf((float)(cursor[s0] + 1));
        const float d1 = rsqrtf((float)(cursor[s1] + 1));
        const float d2 = rsqrtf((float)(cursor[s2] + 1));
        const float d3 = rsqrtf((float)(cursor[s3] + 1));
        acc += x[s0 * F0 + f] * d0 + x[s1 * F0 + f] * d1 +
               x[s2 * F0 + f] * d2 + x[s3 * F0 + f] * d3;
      }
      for (; k < deg; ++k) {
        const int s = col[base + k];
        acc += x[s * F0 + f] * rsqrtf((float)(cursor[s] + 1));
      }
      alds[m * F0 + f] = di * acc;
    }
  }
  __syncthreads();
  {  // phase A: thread = layer-1 channel c; h1[m][c] stride-1 in c
    const int c = tid;
    float w1r[F0];
#pragma unroll
    for (int k = 0; k < F0; ++k) w1r[k] = W1[k * F1 + c];
    const float bb = b1[c];
#pragma unroll
    for (int m = 0; m < MB; ++m) {
      float acc = bb;
#pragma unroll
      for (int k = 0; k < F0; ++k) acc += alds[m * F0 + k] * w1r[k];
      h1[m][c] = fmaxf(acc, 0.f);
    }
  }
  // phase B (R8-exact): 2 nodes x 4 cols per thread; W2 LDS-staged in 32-row
  // chunks, h1 and w2 read as float4.
  const int cg_ = tid & 31;
  const int m0 = (tid >> 5) * 2;
  float a00 = 0.f, a01 = 0.f, a02 = 0.f, a03 = 0.f;
  float a10 = 0.f, a11 = 0.f, a12 = 0.f, a13 = 0.f;
#define FMA4(av, bv, vw)                                            \
  a00 += (av) * (vw).x; a01 += (av) * (vw).y;                       \
  a02 += (av) * (vw).z; a03 += (av) * (vw).w;                       \
  a10 += (bv) * (vw).x; a11 += (bv) * (vw).y;                       \
  a12 += (bv) * (vw).z; a13 += (bv) * (vw).w;
  for (int kc = 0; kc < F1 / 32; ++kc) {
    __syncthreads();  // prev chunk consumed (kc=0: h1 written by phase A)
    {  // stage 32x128 chunk: 1024 float4, 4 per thread, coalesced
      const float4* gsrc = (const float4*)(W2 + kc * 32 * F2);
      float4* ldst = (float4*)w2lds;
#pragma unroll
      for (int i = 0; i < 4; ++i) ldst[tid + 256 * i] = gsrc[tid + 256 * i];
    }
    __syncthreads();
#pragma unroll
    for (int kk = 0; kk < 32; kk += 4) {
      const int k = kc * 32 + kk;
      const float4 ha = *(const float4*)&h1[m0][k];
      const float4 hb = *(const float4*)&h1[m0 + 1][k];
      const float4 w0 = *(const float4*)&w2lds[(kk + 0) * F2 + cg_ * 4];
      const float4 w1v = *(const float4*)&w2lds[(kk + 1) * F2 + cg_ * 4];
      const float4 w2v = *(const float4*)&w2lds[(kk + 2) * F2 + cg_ * 4];
      const float4 w3v = *(const float4*)&w2lds[(kk + 3) * F2 + cg_ * 4];
      FMA4(ha.x, hb.x, w0);
      FMA4(ha.y, hb.y, w1v);
      FMA4(ha.z, hb.z, w2v);
      FMA4(ha.w, hb.w, w3v);
    }
  }
#undef FMA4
  const float d0 = rsqrtf((float)(cursor[n0 + m0] + 1));
  const float d1 = rsqrtf((float)(cursor[n0 + m0 + 1] + 1));
  *(float4*)&t2s[(size_t)(n0 + m0) * F2 + cg_ * 4] =
      make_float4(a00 * d0, a01 * d0, a02 * d0, a03 * d0);
  *(float4*)&t2s[(size_t)(n0 + m0 + 1) * F2 + cg_ * 4] =
      make_float4(a10 * d1, a11 * d1, a12 * d1, a13 * d1);
}

// ---------- layer-2 aggregation + layer-3 transform ----------
// 2 nodes per wave: half-wave (32 lanes) per node, float4 per lane (512B/row).

__global__ __launch_bounds__(256) void k_agg2(
    const float* __restrict__ t2s, const int* __restrict__ cursor,
    const int* __restrict__ col, const float* __restrict__ b2,
    const float* __restrict__ W3, float* __restrict__ t3s) {
  const int wave = (blockIdx.x * 256 + threadIdx.x) >> 6;
  const int lane = threadIdx.x & 63;
  const int half = lane >> 5;        // 0 or 1
  const int li   = lane & 31;
  const int n    = wave * 2 + half;  // 2500 blocks cover 20000 exactly
  if (n >= NN) return;
  const int deg = cursor[n];
  const int base = n * CAP;
  const int fx = li * 4;
  const float4 vs = *(const float4*)&t2s[(size_t)n * F2 + fx];
  float a0 = vs.x, a1 = vs.y, a2 = vs.z, a3 = vs.w;
  int k = 0;
  for (; k + 3 < deg; k += 4) {  // 4 coalesced 512B gathers in flight
    const int s0 = col[base + k],     s1 = col[base + k + 1];
    const int s2 = col[base + k + 2], s3 = col[base + k + 3];
    const float4 v0 = *(const float4*)&t2s[(size_t)s0 * F2 + fx];
    const float4 v1 = *(const float4*)&t2s[(size_t)s1 * F2 + fx];
    const float4 v2 = *(const float4*)&t2s[(size_t)s2 * F2 + fx];
    const float4 v3 = *(const float4*)&t2s[(size_t)s3 * F2 + fx];
    a0 += (v0.x + v1.x) + (v2.x + v3.x);
    a1 += (v0.y + v1.y) + (v2.y + v3.y);
    a2 += (v0.z + v1.z) + (v2.z + v3.z);
    a3 += (v0.w + v1.w) + (v2.w + v3.w);
  }
  for (; k < deg; ++k) {
    const float4 v = *(const float4*)&t2s[(size_t)col[base + k] * F2 + fx];
    a0 += v.x; a1 += v.y; a2 += v.z; a3 += v.w;
  }
  const float di = rsqrtf((float)(deg + 1));
  const float4 bb = *(const float4*)&b2[fx];
  const float4 w3 = *(const float4*)&W3[fx];
  const float h0 = fmaxf(di * a0 + bb.x, 0.f);
  const float h1 = fmaxf(di * a1 + bb.y, 0.f);
  const float h2 = fmaxf(di * a2 + bb.z, 0.f);
  const float h3 = fmaxf(di * a3 + bb.w, 0.f);
  float p = (h0 * w3.x + h1 * w3.y) + (h2 * w3.z + h3 * w3.w);
#pragma unroll
  for (int off = 16; off > 0; off >>= 1) p += __shfl_down(p, off);  // within half
  if (li == 0) t3s[n] = di * p;
}

// ---------- layer-3 aggregation ----------

__global__ void k_agg3(const float* __restrict__ t3s, const int* __restrict__ cursor,
                       const int* __restrict__ col, const float* __restrict__ b3,
                       float* __restrict__ out) {
  int n = blockIdx.x * 256 + threadIdx.x;
  if (n >= NN) return;
  const int deg = cursor[n];
  const int base = n * CAP;
  float acc = t3s[n];
  int k = 0;
  for (; k + 7 < deg; k += 8)
    acc += ((t3s[col[base + k]] + t3s[col[base + k + 1]]) +
            (t3s[col[base + k + 2]] + t3s[col[base + k + 3]])) +
           ((t3s[col[base + k + 4]] + t3s[col[base + k + 5]]) +
            (t3s[col[base + k + 6]] + t3s[col[base + k + 7]]));
  for (; k < deg; ++k) acc += t3s[col[base + k]];
  out[n] = rsqrtf((float)(deg + 1)) * acc + b3[0];
}

extern "C" void kernel_launch(void* const* d_in, const int* in_sizes, int n_in,
                              void* d_out, int out_size, void* d_ws, size_t ws_size,
                              hipStream_t stream) {
  const float* x = (const float*)d_in[0];
  const int* ei = (const int*)d_in[1];
  const int* srcv = ei;       // edge_index[0]
  const int* dstv = ei + NE;  // edge_index[1]
  const float* W1 = (const float*)d_in[2];
  const float* b1 = (const float*)d_in[3];
  const float* W2 = (const float*)d_in[4];
  const float* b2 = (const float*)d_in[5];
  const float* W3 = (const float*)d_in[6];
  const float* b3 = (const float*)d_in[7];
  float* out = (float*)d_out;

  char* w = (char*)d_ws;
  auto alloc = [&](size_t bytes) -> void* {
    void* p = (void*)w;
    w += (bytes + 255) & ~(size_t)255;
    return p;
  };
  int*   cursor = (int*)  alloc(NN * 4);
  int*   col    = (int*)  alloc((size_t)NN * CAP * 4);
  float* t2s    = (float*)alloc((size_t)NN * F2 * 4);
  float* t3s    = (float*)alloc(NN * 4);

  (void)hipMemsetAsync(cursor, 0, NN * 4, stream);
  k_fill<<<(NE + 255) / 256, 256, 0, stream>>>(srcv, dstv, cursor, col);
  k_gemm12<<<NN / MB, 256, 0, stream>>>(x, cursor, col, W1, b1, W2, t2s);
  k_agg2<<<NN / 8, 256, 0, stream>>>(t2s, cursor, col, b2, W3, t3s);
  k_agg3<<<(NN + 255) / 256, 256, 0, stream>>>(t3s, cursor, col, b3, out);
}